// Round 5
// baseline (8644.616 us; speedup 1.0000x reference)
//
#include <hip/hip_runtime.h>
#include <hip/hip_bf16.h>
#include <stdint.h>

// AutoRegressive LSTM (B=1024, T=256, I=64, U=1024, S=64) on MI355X.
// R5: persistent kernel (R3 scaffolding) + weights HALF-PINNED IN LDS.
// Each CU (xcd=row-block, rank=128 gate-cols) pins K-chunks 0..13 (112KB) of
// its weight slice in LDS for all 319 steps; chunks 14+ stream from L2 with a
// counted-vmcnt 3-buf(A)/2-buf(B) pipeline. Kills the 38.8MB/step weight
// re-fetch that capped R2/R3 at ~1.45TB/s of L2-miss traffic.

typedef _Float16 f16;
typedef _Float16 f16x8 __attribute__((ext_vector_type(8)));
typedef float f32x4 __attribute__((ext_vector_type(4)));

#define NKW 34             // warmup K=1088 in 32-chunks
#define NKD 32             // decode K=1024
#define NPIN 14            // K-chunks pinned in LDS (112KB)
#define CH 4096            // halves per chunk tile [128][32]

// swizzled halves-index inside a [128 rows][32 k] fp16 chunk (16B granules)
__device__ __forceinline__ int sw32(int r, int k) {
  return r * 32 + 8 * ((k >> 3) ^ ((r >> 1) & 3)) + (k & 7);
}

// stage one 8KB chunk; wave w covers bytes [w*2048, w*2048+2048) = 2 issues
template <int AUX>
__device__ __forceinline__ void stage_chunk(const f16* __restrict__ g, f16* l, int w, int lane) {
  const char* gp = (const char*)g + w * 2048 + lane * 16;
  char* lp = (char*)l + w * 2048;
#pragma unroll
  for (int i = 0; i < 2; i++) {
    __builtin_amdgcn_global_load_lds(
        (const __attribute__((address_space(1))) unsigned int*)(gp + i * 1024),
        (__attribute__((address_space(3))) unsigned int*)(lp + i * 1024), 16, 0, AUX);
  }
}

// fill the pinned 14-chunk (114,688B) weight block; 28 issues/wave
__device__ __forceinline__ void fill_pin(const f16* __restrict__ src, f16* dst, int w, int lane) {
  const char* gp = (const char*)src;
  char* lp = (char*)dst;
#pragma unroll
  for (int i = 0; i < 28; i++) {
    const int off = w * 28672 + i * 1024;
    __builtin_amdgcn_global_load_lds(
        (const __attribute__((address_space(1))) unsigned int*)(gp + off + lane * 16),
        (__attribute__((address_space(3))) unsigned int*)(lp + off), 16, 0, 0);
  }
}

__device__ __forceinline__ float sigf(float x) { return 1.0f / (1.0f + __expf(-x)); }
__device__ __forceinline__ float tanhfast(float x) { return 1.0f - 2.0f / (__expf(2.0f * x) + 1.0f); }

// ---------------- persistent LSTM kernel ----------------
// grid 256, block 256 (4 waves), 152KB LDS -> 1 WG/CU, 32 WGs/XCD.
// mi = physical XCD (rows 128mi..+127), ni = per-XCD rank (units 32ni..+31).
__global__ void __launch_bounds__(256, 1) lstm_persist(
    const f16* __restrict__ W2, const f16* __restrict__ WP2,
    const float* __restrict__ inputs,
    f16* __restrict__ hbA, f16* __restrict__ xbuf,
    float* __restrict__ ppart,
    const float* __restrict__ bvec, const float* __restrict__ bvec2,
    const float* __restrict__ Wd, const float* __restrict__ bd,
    const int* __restrict__ oidx, float* __restrict__ out,
    int n_idx, unsigned* __restrict__ bar) {
  const int tid = threadIdx.x;

  __shared__ __align__(16) f16 Wp[NPIN * CH];   // 114,688 B pinned weights
  __shared__ __align__(16) f16 Abuf[3][CH];     // 24,576 B
  __shared__ __align__(16) f16 Bbuf[2][CH];     // 16,384 B   total 155,648

  unsigned xcd;
  asm("s_getreg_b32 %0, hwreg(HW_REG_XCC_ID)" : "=s"(xcd));
  xcd &= 7u;
  unsigned* rank_ctr = bar;            // [xcd*16]
  unsigned* bar_cnt = bar + 128;       // [xcd*16]
  unsigned* bar_gen = bar + 256;       // [xcd*16]
  if (tid == 0) {
    unsigned r = __hip_atomic_fetch_add(&rank_ctr[xcd * 16], 1u, __ATOMIC_RELAXED,
                                        __HIP_MEMORY_SCOPE_AGENT) & 31u;
    ((volatile unsigned short*)Bbuf)[0] = (unsigned short)r;
  }
  __syncthreads();
  const int ni = (int)((volatile unsigned short*)Bbuf)[0];
  __syncthreads();
  const int mi = (int)xcd;

  const int w = tid >> 6, lane = tid & 63;
  const int rw = w >> 1, cw = w & 1, ln15 = lane & 15, ln4 = lane >> 4;
  const int u = 32 * ni + 16 * cw + ln15;   // unit owned by this lane

  // biases (plain order), Wd cols for the output head
  float bi_w[4], bi_d[4];
#pragma unroll
  for (int g = 0; g < 4; g++) {
    bi_w[g] = bvec[g * 1024 + u];
    bi_d[g] = bvec2[g * 1024 + u];
  }
  float wdj[8];
#pragma unroll
  for (int j = 0; j < 8; j++) wdj[j] = 0.f;
  for (int j = 0; j < n_idx; j++) wdj[j] = Wd[(size_t)u * 64 + oidx[j]];

  float cst[4][4];
#pragma unroll
  for (int a = 0; a < 4; a++)
#pragma unroll
    for (int q = 0; q < 4; q++) cst[a][q] = 0.f;

  // pin warmup weight chunks 0..13
  fill_pin(W2 + (size_t)ni * NKW * CH, Wp, w, lane);
  asm volatile("s_waitcnt vmcnt(0)" ::: "memory");
  __syncthreads();

  for (int t = 0; t < 319; ++t) {
    // ---- per-XCD barrier ----
    if (tid == 0 && t > 0) {
      int guard = 0;
      while (__hip_atomic_load(&bar_gen[xcd * 16], __ATOMIC_RELAXED,
                               __HIP_MEMORY_SCOPE_AGENT) < (unsigned)t) {
        __builtin_amdgcn_s_sleep(2);
        if (++guard > (1 << 26)) break;
      }
    }
    __builtin_amdgcn_s_barrier();

    const bool warm = (t < 256);
    const int nk = warm ? NKW : NKD;
    const f16* Wsrc = warm ? (W2 + (size_t)ni * NKW * CH) : (WP2 + (size_t)ni * NKD * CH);
    const f16* hA = hbA + (size_t)((t & 1) * 8 + mi) * 32 * CH;
    f16* hW = hbA + (size_t)(((t + 1) & 1) * 8 + mi) * 32 * CH;
    const f16* xb = xbuf + (size_t)((t & 1) * 8 + mi) * 2 * CH;

    // ---- at decode entry: swap pinned weights to W' ----
    if (t == 256) fill_pin(WP2 + (size_t)ni * NKD * CH, Wp, w, lane);

    // ---- reduce previous decode step's output partials ----
    if (t >= 256) {
      const int s = t - 256;
      const int sb = (t - 1) & 1;
      if (tid < 4 * n_idx) {
        const int row = 4 * ni + (tid & 3);
        const int j = tid >> 2;
        float acc = bd[oidx[j]];
        for (int q = 0; q < 32; q++) {
#pragma unroll
          for (int c2 = 0; c2 < 2; c2++) {
            const size_t idx = ((((size_t)(sb * 8 + mi) * 32 + q) * 8 + j) * 2 + c2) * 128 + row;
            acc += __hip_atomic_load(&ppart[idx], __ATOMIC_RELAXED, __HIP_MEMORY_SCOPE_AGENT);
          }
        }
        out[((size_t)(128 * mi + row) * 64 + s) * n_idx + j] = acc;
      }
    }
    asm volatile("s_waitcnt vmcnt(0)" ::: "memory");
    if (t == 256) __builtin_amdgcn_s_barrier();   // pinned W' ready for all waves

    // A-tile source for chunk c
    auto atile = [&](int c) -> const f16* {
      if (warm) return (c < 2) ? (xb + (size_t)c * CH) : (hA + (size_t)(c - 2) * CH);
      return hA + (size_t)c * CH;
    };

    f32x4 acc[4][4];
#pragma unroll
    for (int a = 0; a < 4; a++)
#pragma unroll
      for (int q = 0; q < 4; q++) acc[a][q] = (f32x4){0.f, 0.f, 0.f, 0.f};

    // ---- K loop: pinned LDS W (c<14) + streamed B (c>=14); counted vmcnt ----
    stage_chunk<1>(atile(0), Abuf[0], w, lane);
    stage_chunk<1>(atile(1), Abuf[1], w, lane);
    for (int c = 0; c < nk; ++c) {
      if (c < nk - 1) asm volatile("s_waitcnt vmcnt(2)" ::: "memory");
      else            asm volatile("s_waitcnt vmcnt(0)" ::: "memory");
      __builtin_amdgcn_s_barrier();
      if (c + 1 < nk && c + 1 >= NPIN)
        stage_chunk<0>(Wsrc + (size_t)(c + 1) * CH, Bbuf[(c + 1) & 1], w, lane);
      if (c + 2 < nk)
        stage_chunk<1>(atile(c + 2), Abuf[(c + 2) % 3], w, lane);

      const f16* Ab = Abuf[c % 3];
      const f16* Bb = (c < NPIN) ? (Wp + c * CH) : Bbuf[c & 1];
      f16x8 af[4], bf[4];
#pragma unroll
      for (int mf = 0; mf < 4; mf++)
        af[mf] = *(const f16x8*)(Ab + sw32(64 * rw + 16 * mf + ln15, 8 * ln4));
#pragma unroll
      for (int nf = 0; nf < 4; nf++)
        bf[nf] = *(const f16x8*)(Bb + sw32(64 * cw + 16 * nf + ln15, 8 * ln4));
      __builtin_amdgcn_s_setprio(1);
#pragma unroll
      for (int mf = 0; mf < 4; mf++)
#pragma unroll
        for (int nf = 0; nf < 4; nf++)
          acc[mf][nf] = __builtin_amdgcn_mfma_f32_16x16x32_f16(af[mf], bf[nf], acc[mf][nf], 0, 0, 0);
      __builtin_amdgcn_s_setprio(0);
    }

    // ---- epilogue: gates -> c (regs), h (global swizzled chunk tiles) ----
    const float b0 = warm ? bi_w[0] : bi_d[0];
    const float b1 = warm ? bi_w[1] : bi_d[1];
    const float b2v = warm ? bi_w[2] : bi_d[2];
    const float b3 = warm ? bi_w[3] : bi_d[3];
    f16* ob = hW + (size_t)(u >> 5) * CH;
    const int kh = u & 31;
    float hv[4][4];
#pragma unroll
    for (int mf = 0; mf < 4; mf++) {
#pragma unroll
      for (int reg = 0; reg < 4; reg++) {
        const int r = 64 * rw + 16 * mf + 4 * ln4 + reg;
        const float zi = acc[mf][0][reg] + b0;
        const float zf = acc[mf][1][reg] + b1;
        const float zg = acc[mf][2][reg] + b2v;
        const float zo = acc[mf][3][reg] + b3;
        const float cn = sigf(zf) * cst[mf][reg] + sigf(zi) * tanhfast(zg);
        const float hn = sigf(zo) * tanhfast(cn);
        cst[mf][reg] = cn;
        hv[mf][reg] = hn;
        ob[sw32(r, kh)] = (f16)hn;
      }
    }

    // ---- decode output partials ----
    if (t >= 255) {
      const int sbw = t & 1;
      for (int j = 0; j < n_idx; j++) {
        const float wd = wdj[j];
#pragma unroll
        for (int mf = 0; mf < 4; mf++)
#pragma unroll
          for (int reg = 0; reg < 4; reg++) {
            float v = hv[mf][reg] * wd;
            v += __shfl_xor(v, 1);
            v += __shfl_xor(v, 2);
            v += __shfl_xor(v, 4);
            v += __shfl_xor(v, 8);
            if (ln15 == 0) {
              const int rl = 64 * rw + 16 * mf + 4 * ln4 + reg;
              const size_t idx = ((((size_t)(sbw * 8 + mi) * 32 + ni) * 8 + j) * 2 + cw) * 128 + rl;
              ppart[idx] = v;
            }
          }
      }
    }

    // ---- x-tile prep for next warm step (rank 0 CU) ----
    if (warm && (t + 1 < 256) && ni == 0) {
      const int r = tid >> 1, cx = tid & 1;
      const float* src = inputs + (size_t)(128 * mi + r) * 16384 + (size_t)(t + 1) * 64 + cx * 32;
      f16* xo = xbuf + (size_t)(((t + 1) & 1) * 8 + mi) * 2 * CH + (size_t)cx * CH;
#pragma unroll
      for (int g = 0; g < 4; g++) {
        const float4 a = *(const float4*)(src + g * 8);
        const float4 bq = *(const float4*)(src + g * 8 + 4);
        f16x8 v;
        v[0] = (f16)a.x; v[1] = (f16)a.y; v[2] = (f16)a.z; v[3] = (f16)a.w;
        v[4] = (f16)bq.x; v[5] = (f16)bq.y; v[6] = (f16)bq.z; v[7] = (f16)bq.w;
        *(f16x8*)(xo + r * 32 + 8 * (g ^ ((r >> 1) & 3))) = v;
      }
    }

    // ---- drain, arrive ----
    asm volatile("s_waitcnt vmcnt(0)" ::: "memory");
    __builtin_amdgcn_s_barrier();
    if (tid == 0) {
      unsigned old = __hip_atomic_fetch_add(&bar_cnt[xcd * 16], 1u, __ATOMIC_RELAXED,
                                            __HIP_MEMORY_SCOPE_AGENT);
      if ((old & 31u) == 31u)
        __hip_atomic_fetch_add(&bar_gen[xcd * 16], 1u, __ATOMIC_RELAXED,
                               __HIP_MEMORY_SCOPE_AGENT);
    }
  }

  // ---- final: reduce s=63 partials ----
  if (tid == 0) {
    int guard = 0;
    while (__hip_atomic_load(&bar_gen[xcd * 16], __ATOMIC_RELAXED,
                             __HIP_MEMORY_SCOPE_AGENT) < 319u) {
      __builtin_amdgcn_s_sleep(2);
      if (++guard > (1 << 26)) break;
    }
  }
  __builtin_amdgcn_s_barrier();
  if (tid < 4 * n_idx) {
    const int row = 4 * ni + (tid & 3);
    const int j = tid >> 2;
    float acc = bd[oidx[j]];
    for (int q = 0; q < 32; q++) {
#pragma unroll
      for (int c2 = 0; c2 < 2; c2++) {
        const size_t idx = ((((size_t)(0 * 8 + mi) * 32 + q) * 8 + j) * 2 + c2) * 128 + row;
        acc += __hip_atomic_load(&ppart[idx], __ATOMIC_RELAXED, __HIP_MEMORY_SCOPE_AGENT);
      }
    }
    out[((size_t)(128 * mi + row) * 64 + 63) * n_idx + j] = acc;
  }
}

// ---------------- prep kernels ----------------
// W2[ni][c][128 n][32 k] fp16, swizzled; n -> (cwn=n>>6, gate=(n>>4)&3, j=n&15),
// unit u = 32ni+16cwn+j, source col = gate*1024+u, Kidx = 32c+k.
__global__ void __launch_bounds__(256) prep_W2(const float* __restrict__ Wk,
                                               const float* __restrict__ Wr,
                                               f16* __restrict__ W2) {
  const int blk = blockIdx.x;  // ni*34 + c
  const int ni = blk / NKW, c = blk % NKW;
  f16* ob = W2 + (size_t)blk * CH;
  for (int gi = threadIdx.x; gi < 512; gi += 256) {
    const int n = gi >> 2, g = gi & 3;
    const int cwn = n >> 6, gate = (n >> 4) & 3, j = n & 15;
    const int col = gate * 1024 + 32 * ni + 16 * cwn + j;
    f16x8 v;
#pragma unroll
    for (int e = 0; e < 8; e++) {
      const int kidx = 32 * c + 8 * g + e;
      const float val = (kidx < 64) ? Wk[(size_t)kidx * 4096 + col]
                                    : Wr[(size_t)(kidx - 64) * 4096 + col];
      v[e] = (f16)val;
    }
    *(f16x8*)(ob + n * 32 + 8 * (g ^ ((n >> 1) & 3))) = v;
  }
}

// WP2 = (Wd@Wk + Wr) in the same layout (decode fused weights, K=1024)
__global__ void __launch_bounds__(256) prep_WP2(const float* __restrict__ Wk,
                                                const float* __restrict__ Wr,
                                                const float* __restrict__ Wd,
                                                f16* __restrict__ WP2) {
  const int blk = blockIdx.x;  // ni*32 + c
  const int ni = blk / NKD, c = blk % NKD;
  f16* ob = WP2 + (size_t)blk * CH;
  for (int gi = threadIdx.x; gi < 512; gi += 256) {
    const int n = gi >> 2, g = gi & 3;
    const int cwn = n >> 6, gate = (n >> 4) & 3, j = n & 15;
    const int col = gate * 1024 + 32 * ni + 16 * cwn + j;
    const int uh0 = 32 * c + 8 * g;
    float accv[8];
#pragma unroll
    for (int e = 0; e < 8; e++) accv[e] = Wr[(size_t)(uh0 + e) * 4096 + col];
#pragma unroll
    for (int i = 0; i < 64; i++) {
      const float wki = Wk[(size_t)i * 4096 + col];
#pragma unroll
      for (int e = 0; e < 8; e++)
        accv[e] += Wd[(size_t)(uh0 + e) * 64 + i] * wki;
    }
    f16x8 v;
#pragma unroll
    for (int e = 0; e < 8; e++) v[e] = (f16)accv[e];
    *(f16x8*)(ob + n * 32 + 8 * (g ^ ((n >> 1) & 3))) = v;
  }
}

// b' = b + bd@Wk (plain col order)
__global__ void __launch_bounds__(256) prep_b2(const float* __restrict__ b,
                                               const float* __restrict__ bd,
                                               const float* __restrict__ Wk,
                                               float* __restrict__ bvec2) {
  const int col = blockIdx.x * 256 + threadIdx.x;  // 4096
  float acc = b[col];
#pragma unroll
  for (int i = 0; i < 64; i++) acc += bd[i] * Wk[(size_t)i * 4096 + col];
  bvec2[col] = acc;
}

// x tile for t=0 into xbuf parity 0
__global__ void __launch_bounds__(256) prep_x0(const float* __restrict__ inp, f16* __restrict__ xbuf) {
  const int mi = blockIdx.x, tid = threadIdx.x;
  const int r = tid >> 1, cx = tid & 1;
  const float* src = inp + (size_t)(128 * mi + r) * 16384 + cx * 32;
  f16* xo = xbuf + (size_t)mi * 2 * CH + (size_t)cx * CH;
#pragma unroll
  for (int g = 0; g < 4; g++) {
    const float4 a = *(const float4*)(src + g * 8);
    const float4 b = *(const float4*)(src + g * 8 + 4);
    f16x8 v;
    v[0] = (f16)a.x; v[1] = (f16)a.y; v[2] = (f16)a.z; v[3] = (f16)a.w;
    v[4] = (f16)b.x; v[5] = (f16)b.y; v[6] = (f16)b.z; v[7] = (f16)b.w;
    *(f16x8*)(xo + r * 32 + 8 * (g ^ ((r >> 1) & 3))) = v;
  }
}

// ---------------- host ----------------
extern "C" void kernel_launch(void* const* d_in, const int* in_sizes, int n_in,
                              void* d_out, int out_size, void* d_ws, size_t ws_size,
                              hipStream_t stream) {
  (void)in_sizes; (void)n_in;
  const float* inputs = (const float*)d_in[0];
  const float* Wk = (const float*)d_in[1];
  const float* Wr = (const float*)d_in[2];
  const float* bv = (const float*)d_in[3];
  const float* Wd = (const float*)d_in[4];
  const float* bd = (const float*)d_in[5];
  const int* oidx = (const int*)d_in[6];
  float* out = (float*)d_out;
  const int n_idx = out_size / (1024 * 64);
  if (n_idx < 1 || n_idx > 8) return;

  char* ws = (char*)d_ws;
  const size_t OFF_W2 = 0;                  // 32*34*4096*2 = 8,912,896
  const size_t OFF_WP2 = 8912896;           // 32*32*4096*2 = 8,388,608
  const size_t OFF_B2 = 17301504;           // 16,384
  const size_t OFF_HA = 17317888;           // 2*8*32*4096*2 = 4,194,304
  const size_t OFF_XB = 21512192;           // 2*8*2*4096*2 = 524,288
  const size_t OFF_PP = 22036480;           // 4,194,304
  const size_t OFF_BAR = 26230784;          // 4,096
  const size_t NEED = 26234880;
  if (ws_size < NEED) return;

  f16* W2 = (f16*)(ws + OFF_W2);
  f16* WP2 = (f16*)(ws + OFF_WP2);
  float* bvec2 = (float*)(ws + OFF_B2);
  f16* hbA = (f16*)(ws + OFF_HA);
  f16* xbuf = (f16*)(ws + OFF_XB);
  float* ppart = (float*)(ws + OFF_PP);
  unsigned* bar = (unsigned*)(ws + OFF_BAR);

  hipMemsetAsync(hbA, 0, 2097152, stream);         // h parity-0 = zeros
  hipMemsetAsync(bar, 0, 4096, stream);
  hipLaunchKernelGGL(prep_W2, dim3(32 * NKW), dim3(256), 0, stream, Wk, Wr, W2);
  hipLaunchKernelGGL(prep_WP2, dim3(32 * NKD), dim3(256), 0, stream, Wk, Wr, Wd, WP2);
  hipLaunchKernelGGL(prep_b2, dim3(16), dim3(256), 0, stream, bv, bd, Wk, bvec2);
  hipLaunchKernelGGL(prep_x0, dim3(8), dim3(256), 0, stream, inputs, xbuf);

  hipLaunchKernelGGL(lstm_persist, dim3(256), dim3(256), 0, stream,
                     (const f16*)W2, (const f16*)WP2, inputs,
                     hbA, xbuf, ppart,
                     bv, (const float*)bvec2,
                     Wd, bd, oidx, out, n_idx, bar);
}

// Round 6
// 6890.663 us; speedup vs baseline: 1.2545x; 1.2545x over previous
//
#include <hip/hip_runtime.h>
#include <hip/hip_bf16.h>
#include <stdint.h>

// AutoRegressive LSTM (B=1024, T=256, I=64, U=1024, S=64) on MI355X.
// R6: persistent per-XCD kernel; weights pinned 7 chunks in REGISTERS +
// 4 chunks in LDS; only 6(warm)/5(decode) of 17 BK=64 chunks streamed
// -> per-XCD step footprint ~3.7MB fits the 4MB L2 (R5's 5.1MB thrashed).

typedef _Float16 f16;
typedef _Float16 f16x8 __attribute__((ext_vector_type(8)));
typedef float f32x4 __attribute__((ext_vector_type(4)));

#define NKW2 17            // warmup K=1088 in BK=64 chunks
#define NKD2 16            // decode K=1024
#define RPIN 7             // chunks 0..6 pinned in registers (224 VGPR)
#define LPIN 4             // chunks 7..10 pinned in LDS (64KB)
#define STR0 (RPIN + LPIN) // first streamed chunk = 11
#define TILE_HALVES 8192   // [128][64] fp16 tile = 16KB

// element index inside a [rows][64] fp16 tile, XOR-swizzled (16B granule)
__device__ __forceinline__ int swz(int r, int k) { return (r * 64 + k) ^ ((r & 7) << 3); }

// stage a 16KB tile; wave w covers its quarter (4 issues)
template <int AUX>
__device__ __forceinline__ void stage_tile(const f16* __restrict__ g, f16* l, int w, int lane) {
  const char* gp = (const char*)g + w * 4096 + lane * 16;
  char* lp = (char*)l + w * 4096;
#pragma unroll
  for (int i = 0; i < 4; i++) {
    __builtin_amdgcn_global_load_lds(
        (const __attribute__((address_space(1))) unsigned int*)(gp + i * 1024),
        (__attribute__((address_space(3))) unsigned int*)(lp + i * 1024), 16, 0, AUX);
  }
}

// fill the LDS-pinned 4-chunk (64KB) block; 16 issues/wave
__device__ __forceinline__ void fill_lpin(const f16* __restrict__ src, f16* dst, int w, int lane) {
  const char* gp = (const char*)src;
  char* lp = (char*)dst;
#pragma unroll
  for (int i = 0; i < 16; i++) {
    const int off = w * 16384 + i * 1024;
    __builtin_amdgcn_global_load_lds(
        (const __attribute__((address_space(1))) unsigned int*)(gp + off + lane * 16),
        (__attribute__((address_space(3))) unsigned int*)(lp + off), 16, 0, 0);
  }
}

// load the 7 register-pinned chunks' B-fragments (static indices only)
__device__ __forceinline__ void load_bpin(const f16* __restrict__ panel,
                                          f16x8 (&bp)[RPIN][2][4],
                                          int cw, int ln15, int ln4) {
#pragma unroll
  for (int c = 0; c < RPIN; c++)
#pragma unroll
    for (int kc = 0; kc < 2; kc++)
#pragma unroll
      for (int nf = 0; nf < 4; nf++)
        bp[c][kc][nf] = *(const f16x8*)(panel + (size_t)c * TILE_HALVES +
                                        swz(64 * cw + 16 * nf + ln15, kc * 32 + ln4 * 8));
}

__device__ __forceinline__ float sigf(float x) { return 1.0f / (1.0f + __expf(-x)); }
__device__ __forceinline__ float tanhfast(float x) { return 1.0f - 2.0f / (__expf(2.0f * x) + 1.0f); }

// ---- K loop (fully unrolled; uniform vmcnt(4) ledger) ----
template <int NK, bool WARM>
__device__ __forceinline__ void kloop(
    const f16* __restrict__ xb, const f16* __restrict__ hA, const f16* __restrict__ Wpanel,
    f16 (&Abuf)[3][TILE_HALVES], f16 (&Bbuf)[2][TILE_HALVES], f16* WpL,
    const f16x8 (&bp)[RPIN][2][4], f32x4 (&acc)[4][4],
    int w, int lane, int rw, int cw, int ln15, int ln4) {
  auto atile = [&](int c) -> const f16* {
    if (WARM) return (c == 0) ? xb : (hA + (size_t)(c - 1) * TILE_HALVES);
    return hA + (size_t)c * TILE_HALVES;
  };
  stage_tile<1>(atile(0), Abuf[0], w, lane);
  stage_tile<1>(atile(1), Abuf[1], w, lane);
#pragma unroll
  for (int c = 0; c < NK; c++) {
    if (c < NK - 1) asm volatile("s_waitcnt vmcnt(4)" ::: "memory");
    else            asm volatile("s_waitcnt vmcnt(0)" ::: "memory");
    __builtin_amdgcn_s_barrier();
    if (c + 1 < NK && c + 1 >= STR0)
      stage_tile<0>(Wpanel + (size_t)(c + 1) * TILE_HALVES, Bbuf[(c + 1) & 1], w, lane);
    if (c + 2 < NK)
      stage_tile<1>(atile(c + 2), Abuf[(c + 2) % 3], w, lane);
    const f16* Ab = Abuf[c % 3];
#pragma unroll
    for (int kc = 0; kc < 2; kc++) {
      const int kb = kc * 32 + ln4 * 8;
      f16x8 af[4], bf[4];
#pragma unroll
      for (int mf = 0; mf < 4; mf++)
        af[mf] = *(const f16x8*)(Ab + swz(64 * rw + 16 * mf + ln15, kb));
      if (c < RPIN) {
#pragma unroll
        for (int nf = 0; nf < 4; nf++) bf[nf] = bp[c][kc][nf];
      } else if (c < STR0) {
        const f16* Bb = WpL + (size_t)(c - RPIN) * TILE_HALVES;
#pragma unroll
        for (int nf = 0; nf < 4; nf++)
          bf[nf] = *(const f16x8*)(Bb + swz(64 * cw + 16 * nf + ln15, kb));
      } else {
        const f16* Bb = Bbuf[c & 1];
#pragma unroll
        for (int nf = 0; nf < 4; nf++)
          bf[nf] = *(const f16x8*)(Bb + swz(64 * cw + 16 * nf + ln15, kb));
      }
      __builtin_amdgcn_s_setprio(1);
#pragma unroll
      for (int mf = 0; mf < 4; mf++)
#pragma unroll
        for (int nf = 0; nf < 4; nf++)
          acc[mf][nf] = __builtin_amdgcn_mfma_f32_16x16x32_f16(af[mf], bf[nf], acc[mf][nf], 0, 0, 0);
      __builtin_amdgcn_s_setprio(0);
    }
  }
}

// ---------------- persistent LSTM kernel ----------------
// grid 256, block 256 (4 waves), 144KB LDS -> 1 WG/CU, 32 WGs/XCD.
// mi = physical XCD (rows 128mi..+127), ni = per-XCD rank (units 32ni..+31).
__global__ void __launch_bounds__(256, 1) lstm_persist(
    const f16* __restrict__ W16, const f16* __restrict__ WP16,
    const float* __restrict__ inputs,
    f16* __restrict__ hbA, f16* __restrict__ xbuf,
    float* __restrict__ ppart,
    const float* __restrict__ bperm, const float* __restrict__ bperm2,
    const float* __restrict__ Wd, const float* __restrict__ bd,
    const int* __restrict__ oidx, float* __restrict__ out,
    int n_idx, unsigned* __restrict__ bar) {
  const int tid = threadIdx.x;

  __shared__ __align__(16) f16 WpL[LPIN * TILE_HALVES];  // 64KB pinned weights
  __shared__ __align__(16) f16 Abuf[3][TILE_HALVES];     // 48KB
  __shared__ __align__(16) f16 Bbuf[2][TILE_HALVES];     // 32KB  (total 144KB)
  __shared__ unsigned rank_sh;

  unsigned xcd;
  asm("s_getreg_b32 %0, hwreg(HW_REG_XCC_ID)" : "=s"(xcd));
  xcd &= 7u;
  unsigned* rank_ctr = bar;            // [xcd*16]
  unsigned* bar_cnt = bar + 128;       // [xcd*16]
  unsigned* bar_gen = bar + 256;       // [xcd*16]
  if (tid == 0)
    rank_sh = __hip_atomic_fetch_add(&rank_ctr[xcd * 16], 1u, __ATOMIC_RELAXED,
                                     __HIP_MEMORY_SCOPE_AGENT) & 31u;
  __syncthreads();
  const int mi = (int)xcd;
  const int ni = (int)rank_sh;

  const int w = tid >> 6, lane = tid & 63;
  const int rw = w >> 1, cw = w & 1, ln15 = lane & 15, ln4 = lane >> 4;
  const int u_glob = 32 * ni + 16 * cw + ln15;
  const int kkh = u_glob >> 6, kh = u_glob & 63;

  float biw[4], bi2[4];
#pragma unroll
  for (int nf = 0; nf < 4; nf++) {
    biw[nf] = bperm[ni * 128 + 64 * cw + 16 * nf + ln15];
    bi2[nf] = bperm2[ni * 128 + 64 * cw + 16 * nf + ln15];
  }
  float wdj[8];
#pragma unroll
  for (int j = 0; j < 8; j++) wdj[j] = 0.f;
  for (int j = 0; j < n_idx; j++) wdj[j] = Wd[(size_t)u_glob * 64 + oidx[j]];

  float cst[4][4];
#pragma unroll
  for (int a = 0; a < 4; a++)
#pragma unroll
    for (int q = 0; q < 4; q++) cst[a][q] = 0.f;

  // initial pins: warm weight panel
  f16x8 bpin[RPIN][2][4];
  const f16* Wpw = W16 + (size_t)ni * NKW2 * TILE_HALVES;
  const f16* Wpd = WP16 + (size_t)ni * NKD2 * TILE_HALVES;
  load_bpin(Wpw, bpin, cw, ln15, ln4);
  fill_lpin(Wpw + (size_t)RPIN * TILE_HALVES, WpL, w, lane);
  asm volatile("s_waitcnt vmcnt(0)" ::: "memory");
  __syncthreads();

  for (int t = 0; t < 319; ++t) {
    // ---- per-XCD barrier ----
    if (tid == 0 && t > 0) {
      int guard = 0;
      while (__hip_atomic_load(&bar_gen[xcd * 16], __ATOMIC_RELAXED,
                               __HIP_MEMORY_SCOPE_AGENT) < (unsigned)t) {
        __builtin_amdgcn_s_sleep(2);
        if (++guard > (1 << 26)) break;
      }
    }
    __builtin_amdgcn_s_barrier();

    const bool warm = (t < 256);
    const f16* hA = hbA + (size_t)((t & 1) * 8 + mi) * 16 * TILE_HALVES;
    f16* hW = hbA + (size_t)(((t + 1) & 1) * 8 + mi) * 16 * TILE_HALVES;
    const f16* xb = xbuf + (size_t)((t & 1) * 8 + mi) * TILE_HALVES;

    // ---- reduce previous decode step's output partials ----
    if (t >= 256) {
      const int s = t - 256;
      const int sb = (t - 1) & 1;
      if (tid < 4 * n_idx) {
        const int row = 4 * ni + (tid & 3);
        const int j = tid >> 2;
        float acc = bd[oidx[j]];
        for (int q = 0; q < 32; q++) {
#pragma unroll
          for (int c2 = 0; c2 < 2; c2++) {
            const size_t idx = ((((size_t)(sb * 8 + mi) * 32 + q) * 8 + j) * 2 + c2) * 128 + row;
            acc += __hip_atomic_load(&ppart[idx], __ATOMIC_RELAXED, __HIP_MEMORY_SCOPE_AGENT);
          }
        }
        out[((size_t)(128 * mi + row) * 64 + s) * n_idx + j] = acc;
      }
    }
    // ---- at decode entry: swap pinned weights to W' ----
    if (t == 256) {
      load_bpin(Wpd, bpin, cw, ln15, ln4);
      fill_lpin(Wpd + (size_t)RPIN * TILE_HALVES, WpL, w, lane);
    }
    asm volatile("s_waitcnt vmcnt(0)" ::: "memory");
    if (t == 256) __builtin_amdgcn_s_barrier();

    f32x4 acc[4][4];
#pragma unroll
    for (int a = 0; a < 4; a++)
#pragma unroll
      for (int q = 0; q < 4; q++) acc[a][q] = (f32x4){0.f, 0.f, 0.f, 0.f};

    if (warm) kloop<NKW2, true>(xb, hA, Wpw, Abuf, Bbuf, WpL, bpin, acc, w, lane, rw, cw, ln15, ln4);
    else      kloop<NKD2, false>(xb, hA, Wpd, Abuf, Bbuf, WpL, bpin, acc, w, lane, rw, cw, ln15, ln4);

    // ---- epilogue: gates -> c (regs), h (global swizzled tiles) ----
    const float b0 = warm ? biw[0] : bi2[0];
    const float b1 = warm ? biw[1] : bi2[1];
    const float b2v = warm ? biw[2] : bi2[2];
    const float b3 = warm ? biw[3] : bi2[3];
    f16* ob = hW + (size_t)kkh * TILE_HALVES;
    float hv[4][4];
#pragma unroll
    for (int mf = 0; mf < 4; mf++) {
#pragma unroll
      for (int reg = 0; reg < 4; reg++) {
        const int rl = 64 * rw + 16 * mf + 4 * ln4 + reg;
        const float zi = acc[mf][0][reg] + b0;
        const float zf = acc[mf][1][reg] + b1;
        const float zg = acc[mf][2][reg] + b2v;
        const float zo = acc[mf][3][reg] + b3;
        const float cn = sigf(zf) * cst[mf][reg] + sigf(zi) * tanhfast(zg);
        const float hn = sigf(zo) * tanhfast(cn);
        cst[mf][reg] = cn;
        hv[mf][reg] = hn;
        ob[swz(rl, kh)] = (f16)hn;
      }
    }

    // ---- decode output partials ----
    if (t >= 255) {
      const int sbw = t & 1;
      for (int j = 0; j < n_idx; j++) {
        const float wd = wdj[j];
#pragma unroll
        for (int mf = 0; mf < 4; mf++)
#pragma unroll
          for (int reg = 0; reg < 4; reg++) {
            float v = hv[mf][reg] * wd;
            v += __shfl_xor(v, 1);
            v += __shfl_xor(v, 2);
            v += __shfl_xor(v, 4);
            v += __shfl_xor(v, 8);
            if (ln15 == 0) {
              const int rl = 64 * rw + 16 * mf + 4 * ln4 + reg;
              const size_t idx = ((((size_t)(sbw * 8 + mi) * 32 + ni) * 8 + j) * 2 + cw) * 128 + rl;
              ppart[idx] = v;
            }
          }
      }
    }

    // ---- x-tile prep for next warm step (rank 0 CU) ----
    if (warm && (t + 1 < 256) && ni == 0) {
      const int r = tid >> 1, k0 = (tid & 1) * 32;
      const float* src = inputs + (size_t)(128 * mi + r) * 16384 + (size_t)(t + 1) * 64 + k0;
      f16* xo = xbuf + (size_t)(((t + 1) & 1) * 8 + mi) * TILE_HALVES;
#pragma unroll
      for (int q = 0; q < 4; q++) {
        const float4 a = *(const float4*)(src + q * 8);
        const float4 bq = *(const float4*)(src + q * 8 + 4);
        f16x8 v;
        v[0] = (f16)a.x; v[1] = (f16)a.y; v[2] = (f16)a.z; v[3] = (f16)a.w;
        v[4] = (f16)bq.x; v[5] = (f16)bq.y; v[6] = (f16)bq.z; v[7] = (f16)bq.w;
        *(f16x8*)(xo + swz(r, k0 + 8 * q)) = v;
      }
    }

    // ---- drain, arrive ----
    asm volatile("s_waitcnt vmcnt(0)" ::: "memory");
    __builtin_amdgcn_s_barrier();
    if (tid == 0) {
      unsigned old = __hip_atomic_fetch_add(&bar_cnt[xcd * 16], 1u, __ATOMIC_RELAXED,
                                            __HIP_MEMORY_SCOPE_AGENT);
      if ((old & 31u) == 31u)
        __hip_atomic_fetch_add(&bar_gen[xcd * 16], 1u, __ATOMIC_RELAXED,
                               __HIP_MEMORY_SCOPE_AGENT);
    }
  }

  // ---- final: reduce s=63 partials ----
  if (tid == 0) {
    int guard = 0;
    while (__hip_atomic_load(&bar_gen[xcd * 16], __ATOMIC_RELAXED,
                             __HIP_MEMORY_SCOPE_AGENT) < 319u) {
      __builtin_amdgcn_s_sleep(2);
      if (++guard > (1 << 26)) break;
    }
  }
  __builtin_amdgcn_s_barrier();
  if (tid < 4 * n_idx) {
    const int row = 4 * ni + (tid & 3);
    const int j = tid >> 2;
    float acc = bd[oidx[j]];
    for (int q = 0; q < 32; q++) {
#pragma unroll
      for (int c2 = 0; c2 < 2; c2++) {
        const size_t idx = ((((size_t)mi * 32 + q) * 8 + j) * 2 + c2) * 128 + row;
        acc += __hip_atomic_load(&ppart[idx], __ATOMIC_RELAXED, __HIP_MEMORY_SCOPE_AGENT);
      }
    }
    out[((size_t)(128 * mi + row) * 64 + 63) * n_idx + j] = acc;
  }
}

// ---------------- prep kernels ----------------
// W16: per (ni,kk) a [n=128][k=64] fp16 tile, swizzled. n -> source col:
//   nf=n>>4, j=n&15, gate=nf&3, unit u=32*ni+16*(nf>>2)+j, col=gate*1024+u
__global__ void __launch_bounds__(256) prep_W(const float* __restrict__ Wk,
                                              const float* __restrict__ Wr,
                                              f16* __restrict__ W16) {
  const int blk = blockIdx.x;  // ni*17 + kk
  const int ni = blk / NKW2, kk = blk % NKW2;
  f16* ob = W16 + (size_t)blk * TILE_HALVES;
  for (int c = threadIdx.x; c < 1024; c += 256) {
    const int n = c >> 3, k0 = (c & 7) * 8;
    const int nf = n >> 4, j = n & 15;
    const int gate = nf & 3;
    const int u = 32 * ni + 16 * (nf >> 2) + j;
    const int col = gate * 1024 + u;
    f16x8 v;
#pragma unroll
    for (int e = 0; e < 8; e++) {
      const int kr = kk * 64 + k0 + e;
      const float val = (kr < 64) ? Wk[(size_t)kr * 4096 + col]
                                  : Wr[(size_t)(kr - 64) * 4096 + col];
      v[e] = (f16)val;
    }
    *(f16x8*)(ob + swz(n, k0)) = v;
  }
}

// W' = Wd@Wk + Wr (decode fused weights)
__global__ void __launch_bounds__(256) prep_Wp(const float* __restrict__ Wk,
                                               const float* __restrict__ Wr,
                                               const float* __restrict__ Wd,
                                               f16* __restrict__ WP16) {
  const int blk = blockIdx.x;  // ni*16 + kk
  const int ni = blk / NKD2, kk = blk % NKD2;
  f16* ob = WP16 + (size_t)blk * TILE_HALVES;
  for (int c = threadIdx.x; c < 1024; c += 256) {
    const int n = c >> 3, k0 = (c & 7) * 8;
    const int nf = n >> 4, j = n & 15;
    const int gate = nf & 3;
    const int u = 32 * ni + 16 * (nf >> 2) + j;
    const int col = gate * 1024 + u;
    const int uh0 = kk * 64 + k0;
    float accv[8];
#pragma unroll
    for (int e = 0; e < 8; e++) accv[e] = Wr[(size_t)(uh0 + e) * 4096 + col];
#pragma unroll
    for (int i = 0; i < 64; i++) {
      const float wki = Wk[(size_t)i * 4096 + col];
#pragma unroll
      for (int e = 0; e < 8; e++)
        accv[e] += Wd[(size_t)(uh0 + e) * 64 + i] * wki;
    }
    f16x8 v;
#pragma unroll
    for (int e = 0; e < 8; e++) v[e] = (f16)accv[e];
    *(f16x8*)(ob + swz(n, k0)) = v;
  }
}

__global__ void __launch_bounds__(256) prep_b(const float* __restrict__ b, float* __restrict__ bperm) {
  const int x = blockIdx.x * 256 + threadIdx.x;  // 4096
  const int ni = x >> 7, rem = x & 127, nf = rem >> 4, j = rem & 15;
  bperm[x] = b[(nf & 3) * 1024 + 32 * ni + 16 * (nf >> 2) + j];
}

__global__ void __launch_bounds__(256) prep_b2(const float* __restrict__ b,
                                               const float* __restrict__ bd,
                                               const float* __restrict__ Wk,
                                               float* __restrict__ bperm2) {
  const int x = blockIdx.x * 256 + threadIdx.x;  // 4096
  const int ni = x >> 7, rem = x & 127, nf = rem >> 4, j = rem & 15;
  const int col = (nf & 3) * 1024 + 32 * ni + 16 * (nf >> 2) + j;
  float acc = b[col];
#pragma unroll
  for (int i = 0; i < 64; i++) acc += bd[i] * Wk[(size_t)i * 4096 + col];
  bperm2[x] = acc;
}

// x tile for t=0 into xbuf parity 0
__global__ void __launch_bounds__(256) prep_x0(const float* __restrict__ inp, f16* __restrict__ xbuf) {
  const int mi = blockIdx.x, tid = threadIdx.x;
  const int r = tid >> 1, k0 = (tid & 1) * 32;
  const float* src = inp + (size_t)(128 * mi + r) * 16384 + k0;
  f16* ob = xbuf + (size_t)mi * TILE_HALVES;
#pragma unroll
  for (int q = 0; q < 4; q++) {
    const float4 a = *(const float4*)(src + q * 8);
    const float4 b = *(const float4*)(src + q * 8 + 4);
    f16x8 v;
    v[0] = (f16)a.x; v[1] = (f16)a.y; v[2] = (f16)a.z; v[3] = (f16)a.w;
    v[4] = (f16)b.x; v[5] = (f16)b.y; v[6] = (f16)b.z; v[7] = (f16)b.w;
    *(f16x8*)(ob + swz(r, k0 + 8 * q)) = v;
  }
}

// ---------------- host ----------------
extern "C" void kernel_launch(void* const* d_in, const int* in_sizes, int n_in,
                              void* d_out, int out_size, void* d_ws, size_t ws_size,
                              hipStream_t stream) {
  (void)in_sizes; (void)n_in;
  const float* inputs = (const float*)d_in[0];
  const float* Wk = (const float*)d_in[1];
  const float* Wr = (const float*)d_in[2];
  const float* bv = (const float*)d_in[3];
  const float* Wd = (const float*)d_in[4];
  const float* bd = (const float*)d_in[5];
  const int* oidx = (const int*)d_in[6];
  float* out = (float*)d_out;
  const int n_idx = out_size / (1024 * 64);
  if (n_idx < 1 || n_idx > 8) return;

  char* ws = (char*)d_ws;
  const size_t OFF_W16 = 0;                 // 8,912,896
  const size_t OFF_WP = 8912896;            // 8,388,608
  const size_t OFF_BPERM = 17301504;        // 16,384
  const size_t OFF_BPERM2 = 17317888;       // 16,384
  const size_t OFF_HA = 17334272;           // 4,194,304
  const size_t OFF_XB = 21528576;           // 262,144
  const size_t OFF_PP = 21790720;           // 4,194,304
  const size_t OFF_BAR = 25985024;          // 4,096
  const size_t NEED = 25989120;
  if (ws_size < NEED) return;

  f16* W16 = (f16*)(ws + OFF_W16);
  f16* WP16 = (f16*)(ws + OFF_WP);
  float* bperm = (float*)(ws + OFF_BPERM);
  float* bperm2 = (float*)(ws + OFF_BPERM2);
  f16* hbA = (f16*)(ws + OFF_HA);
  f16* xbuf = (f16*)(ws + OFF_XB);
  float* ppart = (float*)(ws + OFF_PP);
  unsigned* bar = (unsigned*)(ws + OFF_BAR);

  hipMemsetAsync(hbA, 0, 2097152, stream);   // h parity-0 = zeros
  hipMemsetAsync(bar, 0, 4096, stream);
  hipLaunchKernelGGL(prep_W, dim3(32 * NKW2), dim3(256), 0, stream, Wk, Wr, W16);
  hipLaunchKernelGGL(prep_Wp, dim3(32 * NKD2), dim3(256), 0, stream, Wk, Wr, Wd, WP16);
  hipLaunchKernelGGL(prep_b, dim3(16), dim3(256), 0, stream, bv, bperm);
  hipLaunchKernelGGL(prep_b2, dim3(16), dim3(256), 0, stream, bv, bd, Wk, bperm2);
  hipLaunchKernelGGL(prep_x0, dim3(8), dim3(256), 0, stream, inputs, xbuf);

  hipLaunchKernelGGL(lstm_persist, dim3(256), dim3(256), 0, stream,
                     (const f16*)W16, (const f16*)WP16, inputs,
                     hbA, xbuf, ppart,
                     (const float*)bperm, (const float*)bperm2,
                     Wd, bd, oidx, out, n_idx, bar);
}